// Round 13
// baseline (57.913 us; speedup 1.0000x reference)
//
#include <hip/hip_runtime.h>

#define B_ 64
#define T_ 1000
#define C_ 128
#define L_ 100
#define BLANK 127     // C-1
#define LN2F 0.69314718055994530942f
#define FPW 8         // frames per producer wave per phase
#define PH 32         // frames per phase
#define FSTRIDE 1040  // bytes per frame slot: 64*16 (q1,q3 f64 pairs) + 16 (log2pb)
#define BUFSZ (PH * FSTRIDE)

__device__ __forceinline__ float flog2(float x) { return __builtin_amdgcn_logf(x); }

// DPP controls (gfx9/CDNA)
#define DPP_ROW_SHR1   0x111
#define DPP_ROW_SHR2   0x112
#define DPP_ROW_SHR4   0x114
#define DPP_ROW_SHR8   0x118
#define DPP_WAVE_SHR1  0x138   // wave-level: lane i <- lane i-1, crosses rows

template <int CTRL>
__device__ __forceinline__ int dpp_mov(int src) {
    return __builtin_amdgcn_update_dpp(0, src, CTRL, 0xF, 0xF, false);
}

// 5 waves/batch. Producers (wv 1-4): gather p[e1],p[e3],p[blank], compute
// q = (p+eps)/(pb+eps) and log2(pb+eps), store f64 (q1,q3) + f32 log2pb in LDS.
// Consumer (wv 0): q-space f64 recurrence -- blank positions need NO multiply:
//   n0 = a0+pm1; n1 = (a1+a0+m1*pm1)*q1; n2 = a2+a1; n3 = (a3+a2+m3*a1)*q3
// alpha = atilde * prod(pb) * 2^E ; log2 prod(pb) accumulated separately.
__global__ __launch_bounds__(320) void ctc_q_kernel(
    const int* __restrict__ y_true,      // [B, L]
    const float* __restrict__ y_pred,    // [B, T, C]
    const int* __restrict__ in_len,      // [B]
    const int* __restrict__ lab_len,     // [B]
    float* __restrict__ out)             // [B]
{
    const int b   = blockIdx.x;
    const int tid = threadIdx.x;
    const int l   = tid & 63;
    const int wv  = tid >> 6;            // 0 = consumer, 1..4 = producers

    __shared__ __align__(16) char ldsb[2 * BUFSZ];   // 66,560 B

    const int k1 = min(2 * l, L_ - 1);
    const int k3 = min(2 * l + 1, L_ - 1);
    const int e1 = y_true[b * L_ + k1];
    const int e3 = y_true[b * L_ + k3];
    const double m1 = (k1 == 0 || e1 != y_true[b * L_ + k1 - 1]) ? 1.0 : 0.0;
    const double m3 = (e3 != y_true[b * L_ + k3 - 1]) ? 1.0 : 0.0;   // k3 >= 1

    const int Teff = min(T_, in_len[b]);
    const int N      = Teff - 1;         // steps t = 1..N
    const int P_full = N >> 5;
    const int rem    = N & 31;
    const int P      = P_full + (rem ? 1 : 0);
    const float* rowb = y_pred + (size_t)b * T_ * C_;

    double a0 = 0.0, a1 = 0.0, a2 = 0.0, a3 = 0.0;
    double Lsum = 0.0;
    int E = 0;

    // ---- producer: fill this wave's 8 frames of phase phf ----
    auto fillw = [&](int phf) {
        char* bbw = ldsb + (phf & 1) * BUFSZ;
        const int fs_ = (wv - 1) * FPW;
        const int tb_ = 1 + phf * PH + fs_;
        float g10,g30,gb0, g11,g31,gb1, g12,g32,gb2, g13,g33,gb3,
              g14,g34,gb4, g15,g35,gb5, g16,g36,gb6, g17,g37,gb7;
        {
            const float* r_; int tf_;
            tf_ = min(tb_ + 0, N); r_ = rowb + (size_t)tf_ * C_;
            g10 = r_[e1]; g30 = r_[e3]; gb0 = r_[BLANK];
            tf_ = min(tb_ + 1, N); r_ = rowb + (size_t)tf_ * C_;
            g11 = r_[e1]; g31 = r_[e3]; gb1 = r_[BLANK];
            tf_ = min(tb_ + 2, N); r_ = rowb + (size_t)tf_ * C_;
            g12 = r_[e1]; g32 = r_[e3]; gb2 = r_[BLANK];
            tf_ = min(tb_ + 3, N); r_ = rowb + (size_t)tf_ * C_;
            g13 = r_[e1]; g33 = r_[e3]; gb3 = r_[BLANK];
            tf_ = min(tb_ + 4, N); r_ = rowb + (size_t)tf_ * C_;
            g14 = r_[e1]; g34 = r_[e3]; gb4 = r_[BLANK];
            tf_ = min(tb_ + 5, N); r_ = rowb + (size_t)tf_ * C_;
            g15 = r_[e1]; g35 = r_[e3]; gb5 = r_[BLANK];
            tf_ = min(tb_ + 6, N); r_ = rowb + (size_t)tf_ * C_;
            g16 = r_[e1]; g36 = r_[e3]; gb6 = r_[BLANK];
            tf_ = min(tb_ + 7, N); r_ = rowb + (size_t)tf_ * C_;
            g17 = r_[e1]; g37 = r_[e3]; gb7 = r_[BLANK];
        }
        __builtin_amdgcn_sched_barrier(0);   // all loads before all compute/writes
#define PWR(i_, G1, G3, GB) { \
        float rb_ = GB + 1e-7f; \
        float q1_ = (G1 + 1e-7f) / rb_; \
        float q3_ = (G3 + 1e-7f) / rb_; \
        char* q_ = bbw + (fs_ + i_) * FSTRIDE; \
        *(double2*)(q_ + 16 * l) = make_double2((double)q1_, (double)q3_); \
        if (l == 0) *(float*)(q_ + 1024) = flog2(rb_); }
        PWR(0, g10, g30, gb0); PWR(1, g11, g31, gb1);
        PWR(2, g12, g32, gb2); PWR(3, g13, g33, gb3);
        PWR(4, g14, g34, gb4); PWR(5, g15, g35, gb5);
        PWR(6, g16, g36, gb6); PWR(7, g17, g37, gb7);
#undef PWR
    };

#define DECLF(Pr) double Pr##q1, Pr##q3; float Pr##lg
#define LDF(Pr, fi_) { const char* q_ = bbp_ + (fi_) * FSTRIDE; \
    double2 v_ = *(const double2*)(q_ + 16 * l); \
    Pr##q1 = v_.x; Pr##q3 = v_.y; \
    Pr##lg = *(const float*)(q_ + 1024); }

#define STEPQ(Pr) { \
    int slo_ = dpp_mov<DPP_WAVE_SHR1>(__double2loint(a3)); \
    int shi_ = dpp_mov<DPP_WAVE_SHR1>(__double2hiint(a3)); \
    double pm1_ = __hiloint2double(shi_, slo_); \
    double n0_ = a0 + pm1_; \
    double n1_ = (a1 + a0 + m1 * pm1_) * Pr##q1; \
    double n2_ = a2 + a1; \
    double n3_ = (a3 + a2 + m3 * a1) * Pr##q3; \
    lph += Pr##lg; \
    a0 = n0_; a1 = n1_; a2 = n2_; a3 = n3_; }

#define DPPMAX(u_, ctrl_) { unsigned t_ = (unsigned)dpp_mov<ctrl_>((int)(u_)); \
    u_ = max(u_, t_); }
#define RESCALE() { \
    unsigned u_ = max(max((unsigned)__double2hiint(a0), (unsigned)__double2hiint(a1)), \
                      max((unsigned)__double2hiint(a2), (unsigned)__double2hiint(a3))); \
    DPPMAX(u_, DPP_ROW_SHR1); \
    DPPMAX(u_, DPP_ROW_SHR2); \
    DPPMAX(u_, DPP_ROW_SHR4); \
    DPPMAX(u_, DPP_ROW_SHR8); \
    unsigned g_ = max(max((unsigned)__builtin_amdgcn_readlane((int)u_, 15), \
                          (unsigned)__builtin_amdgcn_readlane((int)u_, 31)), \
                      max((unsigned)__builtin_amdgcn_readlane((int)u_, 47), \
                          (unsigned)__builtin_amdgcn_readlane((int)u_, 63))); \
    int kk_ = (int)(g_ >> 20); \
    if (kk_ > 0) { \
        double f_ = __hiloint2double((2046 - kk_) << 20, 0);  /* 2^(1023-kk) exact */ \
        a0 *= f_; a1 *= f_; a2 *= f_; a3 *= f_; \
        E += kk_ - 1023; } }

#define LD8A(bs_) { LDF(A0,(bs_));   LDF(A1,(bs_)+1); LDF(A2,(bs_)+2); LDF(A3,(bs_)+3); \
                    LDF(A4,(bs_)+4); LDF(A5,(bs_)+5); LDF(A6,(bs_)+6); LDF(A7,(bs_)+7); }
#define LD8B(bs_) { LDF(B0,(bs_));   LDF(B1,(bs_)+1); LDF(B2,(bs_)+2); LDF(B3,(bs_)+3); \
                    LDF(B4,(bs_)+4); LDF(B5,(bs_)+5); LDF(B6,(bs_)+6); LDF(B7,(bs_)+7); }
#define S8A() { STEPQ(A0); STEPQ(A1); STEPQ(A2); STEPQ(A3); \
                STEPQ(A4); STEPQ(A5); STEPQ(A6); STEPQ(A7); }
#define S8B() { STEPQ(B0); STEPQ(B1); STEPQ(B2); STEPQ(B3); \
                STEPQ(B4); STEPQ(B5); STEPQ(B6); STEPQ(B7); }

    if (wv >= 1) {
        fillw(0);
    } else {
        // t = 0 init in q-space: atilde[0]=1, atilde[1]=p1/pb; Lsum = log2(pb0)
        float pb0_ = rowb[BLANK] + 1e-7f;
        float p10_ = rowb[e1]    + 1e-7f;
        a0 = (l == 0) ? 1.0 : 0.0;
        a1 = (l == 0) ? (double)(p10_ / pb0_) : 0.0;
        Lsum = (double)flog2(pb0_);
    }
    __syncthreads();

    for (int ph = 0; ph < P; ++ph) {
        if (wv >= 1) {
            if (ph + 1 < P) fillw(ph + 1);
        } else {
            const char* bbp_ = ldsb + (ph & 1) * BUFSZ;
            float lph = 0.f;
            if (ph < P_full) {
                DECLF(A0); DECLF(A1); DECLF(A2); DECLF(A3);
                DECLF(A4); DECLF(A5); DECLF(A6); DECLF(A7);
                DECLF(B0); DECLF(B1); DECLF(B2); DECLF(B3);
                DECLF(B4); DECLF(B5); DECLF(B6); DECLF(B7);
                LD8A(0); LD8B(8);
                S8A();   LD8A(16);
                S8B();   RESCALE();
                         LD8B(24);
                S8A();
                S8B();   RESCALE();
            } else {
                for (int k_ = 0; k_ < rem; ++k_) {
                    DECLF(Tq);
                    LDF(Tq, k_);
                    STEPQ(Tq);
                    if (k_ == 15) RESCALE();
                }
            }
            Lsum += (double)lph;
        }
        __syncthreads();
    }

    if (wv == 0) {
        const int llb = lab_len[b];
        const int pa  = 2 * llb;
        const int qa  = pa >> 2;
        double va = ((pa & 3) == 0) ? __shfl(a0, qa) : __shfl(a2, qa);
        const int pq  = 2 * llb - 1;
        const int qb  = pq >> 2;
        double vb = ((pq & 3) == 1) ? __shfl(a1, qb) : __shfl(a3, qb);
        if (l == 0) {
            double s  = va + vb;             // atilde; alpha = s * 2^(E) * 2^(Lsum)... log2 below
            int hi    = __double2hiint(s);
            int lo    = __double2loint(s);
            int ke    = (hi >> 20) & 0x7FF;
            double mant = __hiloint2double((hi & 0x000FFFFF) | (1023 << 20), lo); // [1,2)
            float r = flog2((float)mant) + (float)(ke - 1023 + E) + (float)Lsum;
            out[b] = -r * LN2F;
        }
    }
}

extern "C" void kernel_launch(void* const* d_in, const int* in_sizes, int n_in,
                              void* d_out, int out_size, void* d_ws, size_t ws_size,
                              hipStream_t stream) {
    const int*   y_true  = (const int*)d_in[0];
    const float* y_pred  = (const float*)d_in[1];
    const int*   in_len  = (const int*)d_in[2];
    const int*   lab_len = (const int*)d_in[3];
    float*       out     = (float*)d_out;

    ctc_q_kernel<<<B_, 320, 0, stream>>>(y_true, y_pred, in_len, lab_len, out);
}

// Round 14
// 44.952 us; speedup vs baseline: 1.2883x; 1.2883x over previous
//
#include <hip/hip_runtime.h>

#define B_ 64
#define T_ 1000
#define C_ 128
#define L_ 100
#define BLANK 127     // C-1
#define LN2F 0.69314718055994530942f
#define FPW 8         // frames per producer wave per phase
#define PH 32         // frames per phase
#define FSTRIDE 1024  // bytes per frame slot: 64 lanes * 16B (q1,q3 f64 pair)
#define BUFSZ (PH * FSTRIDE)

__device__ __forceinline__ float flog2(float x) { return __builtin_amdgcn_logf(x); }
__device__ __forceinline__ float frcp(float x)  { return __builtin_amdgcn_rcpf(x); }

// DPP controls (gfx9/CDNA)
#define DPP_ROW_SHR1   0x111
#define DPP_ROW_SHR2   0x112
#define DPP_ROW_SHR4   0x114
#define DPP_ROW_SHR8   0x118
#define DPP_WAVE_SHR1  0x138   // wave-level: lane i <- lane i-1, crosses rows

template <int CTRL>
__device__ __forceinline__ int dpp_mov(int src) {
    return __builtin_amdgcn_update_dpp(0, src, CTRL, 0xF, 0xF, false);
}

// 5 waves/batch. Producers (wv 1-4): gather p[e1],p[e3],p[blank]; q = p * rcp(pb);
// store f64 (q1,q3) pairs; pre-sum log2(pb) per wave into lgsum. Consumer (wv 0,
// setprio 1): q-space f64 recurrence, 1 ds_read_b128 + 8 f64 + 2 DPP per step.
__global__ __launch_bounds__(320) void ctc_q2_kernel(
    const int* __restrict__ y_true,      // [B, L]
    const float* __restrict__ y_pred,    // [B, T, C]
    const int* __restrict__ in_len,      // [B]
    const int* __restrict__ lab_len,     // [B]
    float* __restrict__ out)             // [B]
{
    const int b   = blockIdx.x;
    const int tid = threadIdx.x;
    const int l   = tid & 63;
    const int wv  = tid >> 6;            // 0 = consumer, 1..4 = producers

    __shared__ __align__(16) char ldsb[2 * BUFSZ];   // 65,536 B
    __shared__ float lgsum[2][4];

    const int k1 = min(2 * l, L_ - 1);
    const int k3 = min(2 * l + 1, L_ - 1);
    const int e1 = y_true[b * L_ + k1];
    const int e3 = y_true[b * L_ + k3];
    const double m1 = (k1 == 0 || e1 != y_true[b * L_ + k1 - 1]) ? 1.0 : 0.0;
    const double m3 = (e3 != y_true[b * L_ + k3 - 1]) ? 1.0 : 0.0;   // k3 >= 1

    const int Teff = min(T_, in_len[b]);
    const int N      = Teff - 1;         // steps t = 1..N
    const int P_full = N >> 5;
    const int rem    = N & 31;
    const int P      = P_full + (rem ? 1 : 0);
    const float* rowb = y_pred + (size_t)b * T_ * C_;

    double a0 = 0.0, a1 = 0.0, a2 = 0.0, a3 = 0.0;
    double Lsum = 0.0;
    int E = 0;

    // ---- producer: fill this wave's 8 frames of phase phf + its lg partial ----
    auto fillw = [&](int phf) {
        char* bbw = ldsb + (phf & 1) * BUFSZ;
        const int fs_ = (wv - 1) * FPW;
        const int tb_ = 1 + phf * PH + fs_;
        float g10,g30,gb0, g11,g31,gb1, g12,g32,gb2, g13,g33,gb3,
              g14,g34,gb4, g15,g35,gb5, g16,g36,gb6, g17,g37,gb7;
        {
            const float* r_; int tf_;
            tf_ = min(tb_ + 0, N); r_ = rowb + (size_t)tf_ * C_;
            g10 = r_[e1]; g30 = r_[e3]; gb0 = r_[BLANK];
            tf_ = min(tb_ + 1, N); r_ = rowb + (size_t)tf_ * C_;
            g11 = r_[e1]; g31 = r_[e3]; gb1 = r_[BLANK];
            tf_ = min(tb_ + 2, N); r_ = rowb + (size_t)tf_ * C_;
            g12 = r_[e1]; g32 = r_[e3]; gb2 = r_[BLANK];
            tf_ = min(tb_ + 3, N); r_ = rowb + (size_t)tf_ * C_;
            g13 = r_[e1]; g33 = r_[e3]; gb3 = r_[BLANK];
            tf_ = min(tb_ + 4, N); r_ = rowb + (size_t)tf_ * C_;
            g14 = r_[e1]; g34 = r_[e3]; gb4 = r_[BLANK];
            tf_ = min(tb_ + 5, N); r_ = rowb + (size_t)tf_ * C_;
            g15 = r_[e1]; g35 = r_[e3]; gb5 = r_[BLANK];
            tf_ = min(tb_ + 6, N); r_ = rowb + (size_t)tf_ * C_;
            g16 = r_[e1]; g36 = r_[e3]; gb6 = r_[BLANK];
            tf_ = min(tb_ + 7, N); r_ = rowb + (size_t)tf_ * C_;
            g17 = r_[e1]; g37 = r_[e3]; gb7 = r_[BLANK];
        }
        __builtin_amdgcn_sched_barrier(0);   // all loads before all compute/writes
        float lgs_ = 0.f;
#define PWR(i_, G1, G3, GB) { \
        float rb_ = GB + 1e-7f; \
        float rc_ = frcp(rb_); \
        float q1_ = (G1 + 1e-7f) * rc_; \
        float q3_ = (G3 + 1e-7f) * rc_; \
        char* q_ = bbw + (fs_ + i_) * FSTRIDE; \
        *(double2*)(q_ + 16 * l) = make_double2((double)q1_, (double)q3_); \
        lgs_ += ((tb_ + i_) <= N) ? flog2(rb_) : 0.f; }
        PWR(0, g10, g30, gb0); PWR(1, g11, g31, gb1);
        PWR(2, g12, g32, gb2); PWR(3, g13, g33, gb3);
        PWR(4, g14, g34, gb4); PWR(5, g15, g35, gb5);
        PWR(6, g16, g36, gb6); PWR(7, g17, g37, gb7);
#undef PWR
        if (l == 0) lgsum[phf & 1][wv - 1] = lgs_;
    };

#define DECLF(Pr) double Pr##q1, Pr##q3
#define LDF(Pr, fi_) { \
    double2 v_ = *(const double2*)(bbp_ + (fi_) * FSTRIDE + 16 * l); \
    Pr##q1 = v_.x; Pr##q3 = v_.y; }

#define STEPQ(Pr) { \
    int slo_ = dpp_mov<DPP_WAVE_SHR1>(__double2loint(a3)); \
    int shi_ = dpp_mov<DPP_WAVE_SHR1>(__double2hiint(a3)); \
    double pm1_ = __hiloint2double(shi_, slo_); \
    double n0_ = a0 + pm1_; \
    double n1_ = (a1 + a0 + m1 * pm1_) * Pr##q1; \
    double n2_ = a2 + a1; \
    double n3_ = (a3 + a2 + m3 * a1) * Pr##q3; \
    a0 = n0_; a1 = n1_; a2 = n2_; a3 = n3_; }

#define DPPMAX(u_, ctrl_) { unsigned t_ = (unsigned)dpp_mov<ctrl_>((int)(u_)); \
    u_ = max(u_, t_); }
#define RESCALE() { \
    unsigned u_ = max(max((unsigned)__double2hiint(a0), (unsigned)__double2hiint(a1)), \
                      max((unsigned)__double2hiint(a2), (unsigned)__double2hiint(a3))); \
    DPPMAX(u_, DPP_ROW_SHR1); \
    DPPMAX(u_, DPP_ROW_SHR2); \
    DPPMAX(u_, DPP_ROW_SHR4); \
    DPPMAX(u_, DPP_ROW_SHR8); \
    unsigned g_ = max(max((unsigned)__builtin_amdgcn_readlane((int)u_, 15), \
                          (unsigned)__builtin_amdgcn_readlane((int)u_, 31)), \
                      max((unsigned)__builtin_amdgcn_readlane((int)u_, 47), \
                          (unsigned)__builtin_amdgcn_readlane((int)u_, 63))); \
    int kk_ = (int)(g_ >> 20); \
    if (kk_ > 0) { \
        double f_ = __hiloint2double((2046 - kk_) << 20, 0);  /* 2^(1023-kk) exact */ \
        a0 *= f_; a1 *= f_; a2 *= f_; a3 *= f_; \
        E += kk_ - 1023; } }

#define LD4A(bs_) { LDF(A0,(bs_)); LDF(A1,(bs_)+1); LDF(A2,(bs_)+2); LDF(A3,(bs_)+3); }
#define LD4B(bs_) { LDF(B0,(bs_)); LDF(B1,(bs_)+1); LDF(B2,(bs_)+2); LDF(B3,(bs_)+3); }
#define S4A() { STEPQ(A0); STEPQ(A1); STEPQ(A2); STEPQ(A3); }
#define S4B() { STEPQ(B0); STEPQ(B1); STEPQ(B2); STEPQ(B3); }

    if (wv >= 1) {
        fillw(0);
    } else {
        __builtin_amdgcn_s_setprio(1);   // consumer owns the critical path
        // t = 0 init in q-space: atilde[0]=1, atilde[1]=p1/pb; Lsum = log2(pb0)
        float pb0_ = rowb[BLANK] + 1e-7f;
        float p10_ = rowb[e1]    + 1e-7f;
        a0 = (l == 0) ? 1.0 : 0.0;
        a1 = (l == 0) ? (double)(p10_ / pb0_) : 0.0;
        Lsum = (double)flog2(pb0_);
    }
    __syncthreads();

    for (int ph = 0; ph < P; ++ph) {
        if (wv >= 1) {
            if (ph + 1 < P) fillw(ph + 1);
        } else {
            const char* bbp_ = ldsb + (ph & 1) * BUFSZ;
            if (ph < P_full) {
                DECLF(A0); DECLF(A1); DECLF(A2); DECLF(A3);
                DECLF(B0); DECLF(B1); DECLF(B2); DECLF(B3);
                LD4A(0);  LD4B(4);
                S4A();    LD4A(8);
                S4B();    LD4B(12);
                S4A();    LD4A(16);
                S4B();    RESCALE();
                          LD4B(20);
                S4A();    LD4A(24);
                S4B();    LD4B(28);
                S4A();
                S4B();    RESCALE();
            } else {
                for (int k_ = 0; k_ < rem; ++k_) {
                    DECLF(Tq);
                    LDF(Tq, k_);
                    STEPQ(Tq);
                    if (k_ == 15) RESCALE();
                }
            }
            Lsum += (double)(lgsum[ph & 1][0] + lgsum[ph & 1][1] +
                             lgsum[ph & 1][2] + lgsum[ph & 1][3]);
        }
        __syncthreads();
    }

    if (wv == 0) {
        const int llb = lab_len[b];
        const int pa  = 2 * llb;
        const int qa  = pa >> 2;
        double va = ((pa & 3) == 0) ? __shfl(a0, qa) : __shfl(a2, qa);
        const int pq  = 2 * llb - 1;
        const int qb  = pq >> 2;
        double vb = ((pq & 3) == 1) ? __shfl(a1, qb) : __shfl(a3, qb);
        if (l == 0) {
            double s  = va + vb;             // atilde
            int hi    = __double2hiint(s);
            int lo    = __double2loint(s);
            int ke    = (hi >> 20) & 0x7FF;
            double mant = __hiloint2double((hi & 0x000FFFFF) | (1023 << 20), lo); // [1,2)
            float r = flog2((float)mant) + (float)(ke - 1023 + E) + (float)Lsum;
            out[b] = -r * LN2F;
        }
    }
}

extern "C" void kernel_launch(void* const* d_in, const int* in_sizes, int n_in,
                              void* d_out, int out_size, void* d_ws, size_t ws_size,
                              hipStream_t stream) {
    const int*   y_true  = (const int*)d_in[0];
    const float* y_pred  = (const float*)d_in[1];
    const int*   in_len  = (const int*)d_in[2];
    const int*   lab_len = (const int*)d_in[3];
    float*       out     = (float*)d_out;

    ctc_q2_kernel<<<B_, 320, 0, stream>>>(y_true, y_pred, in_len, lab_len, out);
}

// Round 15
// 44.143 us; speedup vs baseline: 1.3119x; 1.0183x over previous
//
#include <hip/hip_runtime.h>

#define B_ 64
#define T_ 1000
#define C_ 128
#define L_ 100
#define BLANK 127     // C-1
#define LN2F 0.69314718055994530942f
#define PH 32
#define FSTRIDE 1024  // 64 lanes * 16B (q1,q3 f64 pair)
#define BUFSZ (PH * FSTRIDE)          // 32768
#define OFF_BWD (2 * BUFSZ)           // bwd double-buffer base
#define OFF_AV  (4 * BUFSZ)           // fwd alpha vector exchange (2048B)
#define OFF_LF  (OFF_AV + 2048)
#define OFF_EF  (OFF_LF + 8)
#define OFF_LGF (OFF_LF + 16)         // float[2][4]
#define OFF_LGB (OFF_LGF + 32)        // float[2][4]
#define LDS_SZ  (OFF_LGB + 32)

__device__ __forceinline__ float flog2(float x) { return __builtin_amdgcn_logf(x); }
__device__ __forceinline__ float frcp(float x)  { return __builtin_amdgcn_rcpf(x); }

#define DPP_ROW_SHR1   0x111
#define DPP_ROW_SHR2   0x112
#define DPP_ROW_SHR4   0x114
#define DPP_ROW_SHR8   0x118
#define DPP_WAVE_SHR1  0x138   // lane i <- lane i-1 (validated R8)
#define DPP_WAVE_SHL1  0x130   // lane i <- lane i+1 (mirror)

template <int CTRL>
__device__ __forceinline__ int dpp_mov(int src) {
    return __builtin_amdgcn_update_dpp(0, src, CTRL, 0xF, 0xF, false);
}

// 10 waves/batch: wv0 = fwd consumer, wv1 = bwd consumer, wv2-5 = fwd
// producers, wv6-9 = bwd producers. Loss = sum_s alpha_H[s]*beta_H[s],
// both recurrences in validated q-space f64 with power-of-2 rescaling.
__global__ __launch_bounds__(640) void ctc_bi_kernel(
    const int* __restrict__ y_true, const float* __restrict__ y_pred,
    const int* __restrict__ in_len, const int* __restrict__ lab_len,
    float* __restrict__ out)
{
    const int b   = blockIdx.x;
    const int tid = threadIdx.x;
    const int l   = tid & 63;
    const int wv  = tid >> 6;

    __shared__ __align__(16) char ldsb[LDS_SZ];
    float*  lgf = (float*)(ldsb + OFF_LGF);   // [2][4]
    float*  lgb = (float*)(ldsb + OFF_LGB);   // [2][4]
    double* AV  = (double*)(ldsb + OFF_AV);   // [64][4]
    double* Lfp = (double*)(ldsb + OFF_LF);
    int*    Efp = (int*)(ldsb + OFF_EF);

    const int k1 = min(2 * l, L_ - 1);
    const int k3 = min(2 * l + 1, L_ - 1);
    const int e1 = y_true[b * L_ + k1];
    const int e3 = y_true[b * L_ + k3];
    const double m1 = (k1 == 0 || e1 != y_true[b * L_ + k1 - 1]) ? 1.0 : 0.0;
    const double m3 = (e3 != y_true[b * L_ + k3 - 1]) ? 1.0 : 0.0;
    // lane l+1's m1 (for bwd skip into s=4l+5); l=63 unused (c1n=0)
    const int k1n = min(2 * l + 2, L_ - 1);
    const double m1n = (y_true[b * L_ + k1n] != y_true[b * L_ + k1n - 1]) ? 1.0 : 0.0;

    const int Teff = min(T_, in_len[b]);
    const int N    = Teff - 1;
    const int Hf   = (N + 1) >> 1;       // fwd steps t=1..Hf
    const int Hb   = N - Hf;             // bwd steps t=N..Hf+1
    const int P    = (Hf + 31) >> 5;
    const float* rowb = y_pred + (size_t)b * T_ * C_;

    double a0 = 0.0, a1 = 0.0, a2 = 0.0, a3 = 0.0;   // fwd regs (wv0)
    double b0 = 0.0, b1 = 0.0, b2 = 0.0, b3 = 0.0;   // bwd regs (wv1)
    double Lsum = 0.0;
    int E = 0;

    const bool isProd = (wv >= 2);
    const bool isB    = (wv >= 6);
    const int  fs     = isProd ? ((wv - (isB ? 6 : 2)) * 8) : 0;

    auto fillw = [&](int phf) {
        char* bbw = ldsb + (isB ? OFF_BWD : 0) + (phf & 1) * BUFSZ;
        const int kb_ = phf * PH + fs;
        float g10,g30,gb0, g11,g31,gb1, g12,g32,gb2, g13,g33,gb3,
              g14,g34,gb4, g15,g35,gb5, g16,g36,gb6, g17,g37,gb7;
        int t0_,t1_,t2_,t3_,t4_,t5_,t6_,t7_;
#define FR(i_) (isB ? (N - (kb_ + i_)) : (1 + kb_ + i_))
        t0_=FR(0); t1_=FR(1); t2_=FR(2); t3_=FR(3);
        t4_=FR(4); t5_=FR(5); t6_=FR(6); t7_=FR(7);
#undef FR
        {
            const float* r_;
            r_ = rowb + (size_t)min(max(t0_,1),N) * C_; g10=r_[e1]; g30=r_[e3]; gb0=r_[BLANK];
            r_ = rowb + (size_t)min(max(t1_,1),N) * C_; g11=r_[e1]; g31=r_[e3]; gb1=r_[BLANK];
            r_ = rowb + (size_t)min(max(t2_,1),N) * C_; g12=r_[e1]; g32=r_[e3]; gb2=r_[BLANK];
            r_ = rowb + (size_t)min(max(t3_,1),N) * C_; g13=r_[e1]; g33=r_[e3]; gb3=r_[BLANK];
            r_ = rowb + (size_t)min(max(t4_,1),N) * C_; g14=r_[e1]; g34=r_[e3]; gb4=r_[BLANK];
            r_ = rowb + (size_t)min(max(t5_,1),N) * C_; g15=r_[e1]; g35=r_[e3]; gb5=r_[BLANK];
            r_ = rowb + (size_t)min(max(t6_,1),N) * C_; g16=r_[e1]; g36=r_[e3]; gb6=r_[BLANK];
            r_ = rowb + (size_t)min(max(t7_,1),N) * C_; g17=r_[e1]; g37=r_[e3]; gb7=r_[BLANK];
        }
        __builtin_amdgcn_sched_barrier(0);
        float lgs_ = 0.f;
#define PWR(i_, T_V, G1, G3, GB) { \
        float rb_ = GB + 1e-7f; \
        float rc_ = frcp(rb_); \
        char* q_ = bbw + (kb_ % PH + i_) * FSTRIDE; \
        *(double2*)(q_ + 16 * l) = make_double2((double)((G1 + 1e-7f) * rc_), \
                                                 (double)((G3 + 1e-7f) * rc_)); \
        bool ok_ = isB ? (T_V >= Hf + 1 && T_V <= N) : (T_V >= 1 && T_V <= Hf); \
        lgs_ += ok_ ? flog2(rb_) : 0.f; }
        PWR(0, t0_, g10, g30, gb0); PWR(1, t1_, g11, g31, gb1);
        PWR(2, t2_, g12, g32, gb2); PWR(3, t3_, g13, g33, gb3);
        PWR(4, t4_, g14, g34, gb4); PWR(5, t5_, g15, g35, gb5);
        PWR(6, t6_, g16, g36, gb6); PWR(7, t7_, g17, g37, gb7);
#undef PWR
        if (l == 0) (isB ? lgb : lgf)[(phf & 1) * 4 + (fs >> 3)] = lgs_;
    };

#define DECLF(Pr) double Pr##q1, Pr##q3
#define LDF(Pr, fi_) { \
    double2 v_ = *(const double2*)(bbp_ + (fi_) * FSTRIDE + 16 * l); \
    Pr##q1 = v_.x; Pr##q3 = v_.y; }

#define STEPQ(Pr) { \
    int slo_ = dpp_mov<DPP_WAVE_SHR1>(__double2loint(a3)); \
    int shi_ = dpp_mov<DPP_WAVE_SHR1>(__double2hiint(a3)); \
    double pm1_ = __hiloint2double(shi_, slo_); \
    double n0_ = a0 + pm1_; \
    double n1_ = (a1 + a0 + m1 * pm1_) * Pr##q1; \
    double n2_ = a2 + a1; \
    double n3_ = (a3 + a2 + m3 * a1) * Pr##q3; \
    a0 = n0_; a1 = n1_; a2 = n2_; a3 = n3_; }

#define STEPB(Pr) { \
    double c1_ = b1 * Pr##q1; \
    double c3_ = b3 * Pr##q3; \
    int s0lo_ = dpp_mov<DPP_WAVE_SHL1>(__double2loint(b0)); \
    int s0hi_ = dpp_mov<DPP_WAVE_SHL1>(__double2hiint(b0)); \
    int s1lo_ = dpp_mov<DPP_WAVE_SHL1>(__double2loint(c1_)); \
    int s1hi_ = dpp_mov<DPP_WAVE_SHL1>(__double2hiint(c1_)); \
    double c0n_ = __hiloint2double(s0hi_, s0lo_); \
    double c1n_ = __hiloint2double(s1hi_, s1lo_); \
    double n0_ = b0 + c1_; \
    double n1_ = c1_ + b2 + m3 * c3_; \
    double n2_ = b2 + c3_; \
    double n3_ = c3_ + c0n_ + m1n * c1n_; \
    b0 = n0_; b1 = n1_; b2 = n2_; b3 = n3_; }

#define DPPMAX(u_, ctrl_) { unsigned t_ = (unsigned)dpp_mov<ctrl_>((int)(u_)); \
    u_ = max(u_, t_); }
#define RESCALE4(x0,x1,x2,x3) { \
    unsigned u_ = max(max((unsigned)__double2hiint(x0), (unsigned)__double2hiint(x1)), \
                      max((unsigned)__double2hiint(x2), (unsigned)__double2hiint(x3))); \
    DPPMAX(u_, DPP_ROW_SHR1); \
    DPPMAX(u_, DPP_ROW_SHR2); \
    DPPMAX(u_, DPP_ROW_SHR4); \
    DPPMAX(u_, DPP_ROW_SHR8); \
    unsigned g_ = max(max((unsigned)__builtin_amdgcn_readlane((int)u_, 15), \
                          (unsigned)__builtin_amdgcn_readlane((int)u_, 31)), \
                      max((unsigned)__builtin_amdgcn_readlane((int)u_, 47), \
                          (unsigned)__builtin_amdgcn_readlane((int)u_, 63))); \
    int kk_ = (int)(g_ >> 20); \
    if (kk_ > 0) { \
        double f_ = __hiloint2double((2046 - kk_) << 20, 0); \
        x0 *= f_; x1 *= f_; x2 *= f_; x3 *= f_; \
        E += kk_ - 1023; } }

#define LD4A(bs_) { LDF(A0,(bs_)); LDF(A1,(bs_)+1); LDF(A2,(bs_)+2); LDF(A3,(bs_)+3); }
#define LD4B(bs_) { LDF(B0,(bs_)); LDF(B1,(bs_)+1); LDF(B2,(bs_)+2); LDF(B3,(bs_)+3); }

    if (isProd) {
        fillw(0);
    } else if (wv == 0) {
        __builtin_amdgcn_s_setprio(1);
        float pb0_ = rowb[BLANK] + 1e-7f;
        float p10_ = rowb[e1]    + 1e-7f;
        a0 = (l == 0) ? 1.0 : 0.0;
        a1 = (l == 0) ? (double)(p10_ / pb0_) : 0.0;
        Lsum = (double)flog2(pb0_);
    } else {   // wv == 1: beta init at final frame
        __builtin_amdgcn_s_setprio(1);
        const int llb = lab_len[b];
        const int pa = 2 * llb, pq = 2 * llb - 1;
        b0 = (4 * l     == pa) ? 1.0 : 0.0;
        b1 = (4 * l + 1 == pq) ? 1.0 : 0.0;
        b2 = (4 * l + 2 == pa) ? 1.0 : 0.0;
        b3 = (4 * l + 3 == pq) ? 1.0 : 0.0;
    }
    __syncthreads();

    for (int ph = 0; ph < P; ++ph) {
        if (isProd) {
            if (ph + 1 < P) fillw(ph + 1);
        } else if (wv == 0) {
            const int steps = min(32, Hf - ph * 32);
            const char* bbp_ = ldsb + (ph & 1) * BUFSZ;
            if (steps == 32) {
                DECLF(A0); DECLF(A1); DECLF(A2); DECLF(A3);
                DECLF(B0); DECLF(B1); DECLF(B2); DECLF(B3);
                LD4A(0);  LD4B(4);
                { STEPQ(A0); STEPQ(A1); STEPQ(A2); STEPQ(A3); } LD4A(8);
                { STEPQ(B0); STEPQ(B1); STEPQ(B2); STEPQ(B3); } LD4B(12);
                { STEPQ(A0); STEPQ(A1); STEPQ(A2); STEPQ(A3); } LD4A(16);
                { STEPQ(B0); STEPQ(B1); STEPQ(B2); STEPQ(B3); } RESCALE4(a0,a1,a2,a3);
                          LD4B(20);
                { STEPQ(A0); STEPQ(A1); STEPQ(A2); STEPQ(A3); } LD4A(24);
                { STEPQ(B0); STEPQ(B1); STEPQ(B2); STEPQ(B3); } LD4B(28);
                { STEPQ(A0); STEPQ(A1); STEPQ(A2); STEPQ(A3); }
                { STEPQ(B0); STEPQ(B1); STEPQ(B2); STEPQ(B3); } RESCALE4(a0,a1,a2,a3);
            } else if (steps > 0) {
                for (int k_ = 0; k_ < steps; ++k_) {
                    DECLF(Tq); LDF(Tq, k_); STEPQ(Tq);
                    if (k_ == 15) RESCALE4(a0,a1,a2,a3);
                }
                RESCALE4(a0,a1,a2,a3);
            }
            if (steps > 0)
                Lsum += (double)(lgf[(ph&1)*4+0] + lgf[(ph&1)*4+1] +
                                 lgf[(ph&1)*4+2] + lgf[(ph&1)*4+3]);
        } else {   // wv == 1 (bwd)
            const int steps = min(32, Hb - ph * 32);
            const char* bbp_ = ldsb + OFF_BWD + (ph & 1) * BUFSZ;
            if (steps == 32) {
                DECLF(A0); DECLF(A1); DECLF(A2); DECLF(A3);
                DECLF(B0); DECLF(B1); DECLF(B2); DECLF(B3);
                LD4A(0);  LD4B(4);
                { STEPB(A0); STEPB(A1); STEPB(A2); STEPB(A3); } LD4A(8);
                { STEPB(B0); STEPB(B1); STEPB(B2); STEPB(B3); } LD4B(12);
                { STEPB(A0); STEPB(A1); STEPB(A2); STEPB(A3); } LD4A(16);
                { STEPB(B0); STEPB(B1); STEPB(B2); STEPB(B3); } RESCALE4(b0,b1,b2,b3);
                          LD4B(20);
                { STEPB(A0); STEPB(A1); STEPB(A2); STEPB(A3); } LD4A(24);
                { STEPB(B0); STEPB(B1); STEPB(B2); STEPB(B3); } LD4B(28);
                { STEPB(A0); STEPB(A1); STEPB(A2); STEPB(A3); }
                { STEPB(B0); STEPB(B1); STEPB(B2); STEPB(B3); } RESCALE4(b0,b1,b2,b3);
            } else if (steps > 0) {
                for (int k_ = 0; k_ < steps; ++k_) {
                    DECLF(Tq); LDF(Tq, k_); STEPB(Tq);
                    if (k_ == 15) RESCALE4(b0,b1,b2,b3);
                }
                RESCALE4(b0,b1,b2,b3);
            }
            if (steps > 0)
                Lsum += (double)(lgb[(ph&1)*4+0] + lgb[(ph&1)*4+1] +
                                 lgb[(ph&1)*4+2] + lgb[(ph&1)*4+3]);
        }
        __syncthreads();
    }

    // exchange: fwd consumer publishes alpha_H vector + scalars
    if (wv == 0) {
        AV[4 * l + 0] = a0; AV[4 * l + 1] = a1;
        AV[4 * l + 2] = a2; AV[4 * l + 3] = a3;
        if (l == 0) { *Lfp = Lsum; *Efp = E; }
    }
    __syncthreads();

    if (wv == 1) {
        double d = AV[4*l+0]*b0 + AV[4*l+1]*b1 + AV[4*l+2]*b2 + AV[4*l+3]*b3;
        d += __shfl_xor(d, 1);  d += __shfl_xor(d, 2);  d += __shfl_xor(d, 4);
        d += __shfl_xor(d, 8);  d += __shfl_xor(d, 16); d += __shfl_xor(d, 32);
        if (l == 0) {
            double Ltot = Lsum + *Lfp;
            int Etot = E + *Efp;
            int hi = __double2hiint(d), lo = __double2loint(d);
            int ke = (hi >> 20) & 0x7FF;
            double mant = __hiloint2double((hi & 0x000FFFFF) | (1023 << 20), lo);
            float r = flog2((float)mant) + (float)(ke - 1023 + Etot) + (float)Ltot;
            out[b] = -r * LN2F;
        }
    }
}

extern "C" void kernel_launch(void* const* d_in, const int* in_sizes, int n_in,
                              void* d_out, int out_size, void* d_ws, size_t ws_size,
                              hipStream_t stream) {
    const int*   y_true  = (const int*)d_in[0];
    const float* y_pred  = (const float*)d_in[1];
    const int*   in_len  = (const int*)d_in[2];
    const int*   lab_len = (const int*)d_in[3];
    float*       out     = (float*)d_out;

    ctc_bi_kernel<<<B_, 640, 0, stream>>>(y_true, y_pred, in_len, lab_len, out);
}

// Round 16
// 34.805 us; speedup vs baseline: 1.6639x; 1.2683x over previous
//
#include <hip/hip_runtime.h>

#define B_ 64
#define T_ 1000
#define C_ 128
#define L_ 100
#define BLANK 127     // C-1
#define LN2F 0.69314718055994530942f
#define PH 32
#define FSTRIDE 1024  // 64 lanes * 16B (q1,q3 f64 pair)
#define BUFSZ (PH * FSTRIDE)          // 32768

__device__ __forceinline__ float flog2(float x) { return __builtin_amdgcn_logf(x); }
__device__ __forceinline__ float frcp(float x)  { return __builtin_amdgcn_rcpf(x); }

#define DPP_ROW_SHR1   0x111
#define DPP_ROW_SHR2   0x112
#define DPP_ROW_SHR4   0x114
#define DPP_ROW_SHR8   0x118
#define DPP_WAVE_SHR1  0x138   // lane i <- lane i-1 (validated R8)
#define DPP_WAVE_SHL1  0x130   // lane i <- lane i+1 (validated R15)

template <int CTRL>
__device__ __forceinline__ int dpp_mov(int src) {
    return __builtin_amdgcn_update_dpp(0, src, CTRL, 0xF, 0xF, false);
}

// 128 blocks x 5 waves. Blocks 0-63: forward half (R14's exact validated
// shape). Blocks 64-127: backward half (STEPB-v2: prev-step DPP + neighbor-q
// from LDS -> chain length equals fwd). Results exchanged via d_ws; combine
// kernel does the alpha.beta dot product.
__global__ __launch_bounds__(320) void ctc_split_kernel(
    const int* __restrict__ y_true, const float* __restrict__ y_pred,
    const int* __restrict__ in_len, const int* __restrict__ lab_len,
    double* __restrict__ AVf, double* __restrict__ AVb,
    double* __restrict__ Ls, int* __restrict__ Es)
{
    const int bb    = blockIdx.x & 63;
    const bool isB  = blockIdx.x >= 64;
    const int tid   = threadIdx.x;
    const int l     = tid & 63;
    const int wv    = tid >> 6;          // 0 = consumer, 1..4 = producers

    __shared__ __align__(16) char ldsb[2 * BUFSZ + 64];
    __shared__ float lgs[2][4];

    const int k1 = min(2 * l, L_ - 1);
    const int k3 = min(2 * l + 1, L_ - 1);
    const int e1 = y_true[bb * L_ + k1];
    const int e3 = y_true[bb * L_ + k3];
    const double m1 = (k1 == 0 || e1 != y_true[bb * L_ + k1 - 1]) ? 1.0 : 0.0;
    const double m3 = (e3 != y_true[bb * L_ + k3 - 1]) ? 1.0 : 0.0;
    const int k1n = min(2 * l + 2, L_ - 1);
    const double m1n = (y_true[bb * L_ + k1n] != y_true[bb * L_ + k1n - 1]) ? 1.0 : 0.0;

    const int Teff = min(T_, in_len[bb]);
    const int N    = Teff - 1;
    const int Hf   = (N + 1) >> 1;
    const int Hb   = N - Hf;
    const int steps_total = isB ? Hb : Hf;
    const int P_full = steps_total >> 5;
    const int rem    = steps_total & 31;
    const int P      = P_full + (rem ? 1 : 0);
    const float* rowb = y_pred + (size_t)bb * T_ * C_;

    double a0 = 0.0, a1 = 0.0, a2 = 0.0, a3 = 0.0;
    double Lsum = 0.0;
    int E = 0;

    const int fs = (wv - 1) * 8;

    auto fillw = [&](int phf) {
        char* bbw = ldsb + (phf & 1) * BUFSZ;
        const int kb_ = phf * PH + fs;
        float g10,g30,gb0, g11,g31,gb1, g12,g32,gb2, g13,g33,gb3,
              g14,g34,gb4, g15,g35,gb5, g16,g36,gb6, g17,g37,gb7;
        int t0_,t1_,t2_,t3_,t4_,t5_,t6_,t7_;
#define FR(i_) (isB ? (N - (kb_ + i_)) : (1 + kb_ + i_))
        t0_=FR(0); t1_=FR(1); t2_=FR(2); t3_=FR(3);
        t4_=FR(4); t5_=FR(5); t6_=FR(6); t7_=FR(7);
#undef FR
        {
            const float* r_;
            r_ = rowb + (size_t)min(max(t0_,1),N) * C_; g10=r_[e1]; g30=r_[e3]; gb0=r_[BLANK];
            r_ = rowb + (size_t)min(max(t1_,1),N) * C_; g11=r_[e1]; g31=r_[e3]; gb1=r_[BLANK];
            r_ = rowb + (size_t)min(max(t2_,1),N) * C_; g12=r_[e1]; g32=r_[e3]; gb2=r_[BLANK];
            r_ = rowb + (size_t)min(max(t3_,1),N) * C_; g13=r_[e1]; g33=r_[e3]; gb3=r_[BLANK];
            r_ = rowb + (size_t)min(max(t4_,1),N) * C_; g14=r_[e1]; g34=r_[e3]; gb4=r_[BLANK];
            r_ = rowb + (size_t)min(max(t5_,1),N) * C_; g15=r_[e1]; g35=r_[e3]; gb5=r_[BLANK];
            r_ = rowb + (size_t)min(max(t6_,1),N) * C_; g16=r_[e1]; g36=r_[e3]; gb6=r_[BLANK];
            r_ = rowb + (size_t)min(max(t7_,1),N) * C_; g17=r_[e1]; g37=r_[e3]; gb7=r_[BLANK];
        }
        __builtin_amdgcn_sched_barrier(0);
        float lgs_ = 0.f;
#define PWR(i_, T_V, G1, G3, GB) { \
        float rb_ = GB + 1e-7f; \
        float rc_ = frcp(rb_); \
        char* q_ = bbw + ((kb_ & 31) + i_) * FSTRIDE; \
        *(double2*)(q_ + 16 * l) = make_double2((double)((G1 + 1e-7f) * rc_), \
                                                 (double)((G3 + 1e-7f) * rc_)); \
        bool ok_ = isB ? (T_V >= Hf + 1 && T_V <= N) : (T_V >= 1 && T_V <= Hf); \
        lgs_ += ok_ ? flog2(rb_) : 0.f; }
        PWR(0, t0_, g10, g30, gb0); PWR(1, t1_, g11, g31, gb1);
        PWR(2, t2_, g12, g32, gb2); PWR(3, t3_, g13, g33, gb3);
        PWR(4, t4_, g14, g34, gb4); PWR(5, t5_, g15, g35, gb5);
        PWR(6, t6_, g16, g36, gb6); PWR(7, t7_, g17, g37, gb7);
#undef PWR
        if (l == 0) lgs[phf & 1][wv - 1] = lgs_;
    };

#define DECLF(Pr) double Pr##q1, Pr##q3
#define DECLB(Pr) double Pr##q1, Pr##q3, Pr##q1n
#define LDF(Pr, fi_) { \
    double2 v_ = *(const double2*)(bbp_ + (fi_) * FSTRIDE + 16 * l); \
    Pr##q1 = v_.x; Pr##q3 = v_.y; }
#define LDFB(Pr, fi_) { \
    double2 v_ = *(const double2*)(bbp_ + (fi_) * FSTRIDE + 16 * l); \
    Pr##q1 = v_.x; Pr##q3 = v_.y; \
    Pr##q1n = *(const double*)(bbp_ + (fi_) * FSTRIDE + 16 * ((l + 1) & 63)); }

#define STEPQ(Pr) { \
    int slo_ = dpp_mov<DPP_WAVE_SHR1>(__double2loint(a3)); \
    int shi_ = dpp_mov<DPP_WAVE_SHR1>(__double2hiint(a3)); \
    double pm1_ = __hiloint2double(shi_, slo_); \
    double n0_ = a0 + pm1_; \
    double n1_ = (a1 + a0 + m1 * pm1_) * Pr##q1; \
    double n2_ = a2 + a1; \
    double n3_ = (a3 + a2 + m3 * a1) * Pr##q3; \
    a0 = n0_; a1 = n1_; a2 = n2_; a3 = n3_; }

// v2: neighbor terms from prev-step regs (DPP hoistable) + neighbor q via LDS
#define STEPB(Pr) { \
    int n0lo_ = dpp_mov<DPP_WAVE_SHL1>(__double2loint(a0)); \
    int n0hi_ = dpp_mov<DPP_WAVE_SHL1>(__double2hiint(a0)); \
    int n1lo_ = dpp_mov<DPP_WAVE_SHL1>(__double2loint(a1)); \
    int n1hi_ = dpp_mov<DPP_WAVE_SHL1>(__double2hiint(a1)); \
    double b0n_ = __hiloint2double(n0hi_, n0lo_); \
    double b1n_ = __hiloint2double(n1hi_, n1lo_); \
    double c1_ = a1 * Pr##q1; \
    double c3_ = a3 * Pr##q3; \
    double c1n_ = b1n_ * Pr##q1n; \
    double n0_ = a0 + c1_; \
    double n1_ = c1_ + a2 + m3 * c3_; \
    double n2_ = a2 + c3_; \
    double n3_ = c3_ + b0n_ + m1n * c1n_; \
    a0 = n0_; a1 = n1_; a2 = n2_; a3 = n3_; }

#define DPPMAX(u_, ctrl_) { unsigned t_ = (unsigned)dpp_mov<ctrl_>((int)(u_)); \
    u_ = max(u_, t_); }
#define RESCALE() { \
    unsigned u_ = max(max((unsigned)__double2hiint(a0), (unsigned)__double2hiint(a1)), \
                      max((unsigned)__double2hiint(a2), (unsigned)__double2hiint(a3))); \
    DPPMAX(u_, DPP_ROW_SHR1); \
    DPPMAX(u_, DPP_ROW_SHR2); \
    DPPMAX(u_, DPP_ROW_SHR4); \
    DPPMAX(u_, DPP_ROW_SHR8); \
    unsigned g_ = max(max((unsigned)__builtin_amdgcn_readlane((int)u_, 15), \
                          (unsigned)__builtin_amdgcn_readlane((int)u_, 31)), \
                      max((unsigned)__builtin_amdgcn_readlane((int)u_, 47), \
                          (unsigned)__builtin_amdgcn_readlane((int)u_, 63))); \
    int kk_ = (int)(g_ >> 20); \
    if (kk_ > 0) { \
        double f_ = __hiloint2double((2046 - kk_) << 20, 0); \
        a0 *= f_; a1 *= f_; a2 *= f_; a3 *= f_; \
        E += kk_ - 1023; } }

    if (wv >= 1) {
        fillw(0);
    } else if (!isB) {
        __builtin_amdgcn_s_setprio(1);
        float pb0_ = rowb[BLANK] + 1e-7f;
        float p10_ = rowb[e1]    + 1e-7f;
        a0 = (l == 0) ? 1.0 : 0.0;
        a1 = (l == 0) ? (double)(p10_ / pb0_) : 0.0;
        Lsum = (double)flog2(pb0_);
    } else {
        __builtin_amdgcn_s_setprio(1);
        const int llb = lab_len[bb];
        const int pa = 2 * llb, pq = 2 * llb - 1;
        a0 = (4 * l     == pa) ? 1.0 : 0.0;
        a1 = (4 * l + 1 == pq) ? 1.0 : 0.0;
        a2 = (4 * l + 2 == pa) ? 1.0 : 0.0;
        a3 = (4 * l + 3 == pq) ? 1.0 : 0.0;
    }
    __syncthreads();

    for (int ph = 0; ph < P; ++ph) {
        if (wv >= 1) {
            if (ph + 1 < P) fillw(ph + 1);
        } else {
            const char* bbp_ = ldsb + (ph & 1) * BUFSZ;
            const int steps = (ph < P_full) ? 32 : rem;
            if (!isB) {
                if (steps == 32) {
                    DECLF(A0); DECLF(A1); DECLF(A2); DECLF(A3);
                    DECLF(B0); DECLF(B1); DECLF(B2); DECLF(B3);
                    LDF(A0,0); LDF(A1,1); LDF(A2,2); LDF(A3,3);
                    LDF(B0,4); LDF(B1,5); LDF(B2,6); LDF(B3,7);
                    { STEPQ(A0); STEPQ(A1); STEPQ(A2); STEPQ(A3); }
                    LDF(A0,8); LDF(A1,9); LDF(A2,10); LDF(A3,11);
                    { STEPQ(B0); STEPQ(B1); STEPQ(B2); STEPQ(B3); }
                    LDF(B0,12); LDF(B1,13); LDF(B2,14); LDF(B3,15);
                    { STEPQ(A0); STEPQ(A1); STEPQ(A2); STEPQ(A3); }
                    LDF(A0,16); LDF(A1,17); LDF(A2,18); LDF(A3,19);
                    { STEPQ(B0); STEPQ(B1); STEPQ(B2); STEPQ(B3); } RESCALE();
                    LDF(B0,20); LDF(B1,21); LDF(B2,22); LDF(B3,23);
                    { STEPQ(A0); STEPQ(A1); STEPQ(A2); STEPQ(A3); }
                    LDF(A0,24); LDF(A1,25); LDF(A2,26); LDF(A3,27);
                    { STEPQ(B0); STEPQ(B1); STEPQ(B2); STEPQ(B3); }
                    LDF(B0,28); LDF(B1,29); LDF(B2,30); LDF(B3,31);
                    { STEPQ(A0); STEPQ(A1); STEPQ(A2); STEPQ(A3); }
                    { STEPQ(B0); STEPQ(B1); STEPQ(B2); STEPQ(B3); } RESCALE();
                } else {
                    for (int k_ = 0; k_ < steps; ++k_) {
                        DECLF(Tq); LDF(Tq, k_); STEPQ(Tq);
                        if (k_ == 15) RESCALE();
                    }
                    RESCALE();
                }
            } else {
                if (steps == 32) {
                    DECLB(A0); DECLB(A1); DECLB(A2); DECLB(A3);
                    DECLB(B0); DECLB(B1); DECLB(B2); DECLB(B3);
                    LDFB(A0,0); LDFB(A1,1); LDFB(A2,2); LDFB(A3,3);
                    LDFB(B0,4); LDFB(B1,5); LDFB(B2,6); LDFB(B3,7);
                    { STEPB(A0); STEPB(A1); STEPB(A2); STEPB(A3); }
                    LDFB(A0,8); LDFB(A1,9); LDFB(A2,10); LDFB(A3,11);
                    { STEPB(B0); STEPB(B1); STEPB(B2); STEPB(B3); }
                    LDFB(B0,12); LDFB(B1,13); LDFB(B2,14); LDFB(B3,15);
                    { STEPB(A0); STEPB(A1); STEPB(A2); STEPB(A3); }
                    LDFB(A0,16); LDFB(A1,17); LDFB(A2,18); LDFB(A3,19);
                    { STEPB(B0); STEPB(B1); STEPB(B2); STEPB(B3); } RESCALE();
                    LDFB(B0,20); LDFB(B1,21); LDFB(B2,22); LDFB(B3,23);
                    { STEPB(A0); STEPB(A1); STEPB(A2); STEPB(A3); }
                    LDFB(A0,24); LDFB(A1,25); LDFB(A2,26); LDFB(A3,27);
                    { STEPB(B0); STEPB(B1); STEPB(B2); STEPB(B3); }
                    LDFB(B0,28); LDFB(B1,29); LDFB(B2,30); LDFB(B3,31);
                    { STEPB(A0); STEPB(A1); STEPB(A2); STEPB(A3); }
                    { STEPB(B0); STEPB(B1); STEPB(B2); STEPB(B3); } RESCALE();
                } else {
                    for (int k_ = 0; k_ < steps; ++k_) {
                        DECLB(Tq); LDFB(Tq, k_); STEPB(Tq);
                        if (k_ == 15) RESCALE();
                    }
                    RESCALE();
                }
            }
            Lsum += (double)(lgs[ph & 1][0] + lgs[ph & 1][1] +
                             lgs[ph & 1][2] + lgs[ph & 1][3]);
        }
        __syncthreads();
    }

    if (wv == 0) {
        double* AV = (isB ? AVb : AVf) + bb * 256;
        AV[4 * l + 0] = a0; AV[4 * l + 1] = a1;
        AV[4 * l + 2] = a2; AV[4 * l + 3] = a3;
        if (l == 0) {
            Ls[bb * 2 + (isB ? 1 : 0)] = Lsum;
            Es[bb * 2 + (isB ? 1 : 0)] = E;
        }
    }
}

__global__ __launch_bounds__(64) void ctc_combine_kernel(
    const double* __restrict__ AVf, const double* __restrict__ AVb,
    const double* __restrict__ Ls, const int* __restrict__ Es,
    float* __restrict__ out)
{
    const int b = blockIdx.x;
    const int l = threadIdx.x;
    const double* f = AVf + b * 256;
    const double* g = AVb + b * 256;
    double d = f[4*l+0]*g[4*l+0] + f[4*l+1]*g[4*l+1]
             + f[4*l+2]*g[4*l+2] + f[4*l+3]*g[4*l+3];
    d += __shfl_xor(d, 1);  d += __shfl_xor(d, 2);  d += __shfl_xor(d, 4);
    d += __shfl_xor(d, 8);  d += __shfl_xor(d, 16); d += __shfl_xor(d, 32);
    if (l == 0) {
        double Ltot = Ls[b * 2] + Ls[b * 2 + 1];
        int    Etot = Es[b * 2] + Es[b * 2 + 1];
        int hi = __double2hiint(d), lo = __double2loint(d);
        int ke = (hi >> 20) & 0x7FF;
        double mant = __hiloint2double((hi & 0x000FFFFF) | (1023 << 20), lo);
        float r = flog2((float)mant) + (float)(ke - 1023 + Etot) + (float)Ltot;
        out[b] = -r * LN2F;
    }
}

extern "C" void kernel_launch(void* const* d_in, const int* in_sizes, int n_in,
                              void* d_out, int out_size, void* d_ws, size_t ws_size,
                              hipStream_t stream) {
    const int*   y_true  = (const int*)d_in[0];
    const float* y_pred  = (const float*)d_in[1];
    const int*   in_len  = (const int*)d_in[2];
    const int*   lab_len = (const int*)d_in[3];
    float*       out     = (float*)d_out;

    double* AVf = (double*)d_ws;                 // [64][256]
    double* AVb = AVf + 64 * 256;                // [64][256]
    double* Ls  = AVb + 64 * 256;                // [64][2]
    int*    Es  = (int*)(Ls + 128);              // [64][2]

    ctc_split_kernel<<<128, 320, 0, stream>>>(y_true, y_pred, in_len, lab_len,
                                              AVf, AVb, Ls, Es);
    ctc_combine_kernel<<<64, 64, 0, stream>>>(AVf, AVb, Ls, Es, out);
}

// Round 17
// 33.743 us; speedup vs baseline: 1.7163x; 1.0315x over previous
//
#include <hip/hip_runtime.h>

#define B_ 64
#define T_ 1000
#define C_ 128
#define L_ 100
#define BLANK 127     // C-1
#define LN2F 0.69314718055994530942f
#define PH 64
#define NPROD 8
#define FSTRIDE 1024  // 64 lanes * 16B (q1,q3 f64 pair)
#define BUFSZ (PH * FSTRIDE)          // 65536

__device__ __forceinline__ float flog2(float x) { return __builtin_amdgcn_logf(x); }
__device__ __forceinline__ float frcp(float x)  { return __builtin_amdgcn_rcpf(x); }

#define DPP_ROW_SHR1   0x111
#define DPP_ROW_SHR2   0x112
#define DPP_ROW_SHR4   0x114
#define DPP_ROW_SHR8   0x118
#define DPP_WAVE_SHR1  0x138   // lane i <- lane i-1 (validated R8)
#define DPP_WAVE_SHL1  0x130   // lane i <- lane i+1 (validated R15/R16)

template <int CTRL>
__device__ __forceinline__ int dpp_mov(int src) {
    return __builtin_amdgcn_update_dpp(0, src, CTRL, 0xF, 0xF, false);
}

// 128 blocks x 9 waves (1 consumer + 8 producers). Blocks 0-63 forward,
// 64-127 backward (validated R16 math). PH=64: half the barriers of R16;
// 8 producer waves double gather MLP. LDS 128 KiB double buffer.
__global__ __launch_bounds__(576) void ctc_split_kernel(
    const int* __restrict__ y_true, const float* __restrict__ y_pred,
    const int* __restrict__ in_len, const int* __restrict__ lab_len,
    double* __restrict__ AVf, double* __restrict__ AVb,
    double* __restrict__ Ls, int* __restrict__ Es)
{
    const int bb    = blockIdx.x & 63;
    const bool isB  = blockIdx.x >= 64;
    const int tid   = threadIdx.x;
    const int l     = tid & 63;
    const int wv    = tid >> 6;          // 0 = consumer, 1..8 = producers

    __shared__ __align__(16) char ldsb[2 * BUFSZ];
    __shared__ float lgs[2][NPROD];

    const int k1 = min(2 * l, L_ - 1);
    const int k3 = min(2 * l + 1, L_ - 1);
    const int e1 = y_true[bb * L_ + k1];
    const int e3 = y_true[bb * L_ + k3];
    const double m1 = (k1 == 0 || e1 != y_true[bb * L_ + k1 - 1]) ? 1.0 : 0.0;
    const double m3 = (e3 != y_true[bb * L_ + k3 - 1]) ? 1.0 : 0.0;
    const int k1n = min(2 * l + 2, L_ - 1);
    const double m1n = (y_true[bb * L_ + k1n] != y_true[bb * L_ + k1n - 1]) ? 1.0 : 0.0;

    const int Teff = min(T_, in_len[bb]);
    const int N    = Teff - 1;
    const int Hf   = (N + 1) >> 1;
    const int Hb   = N - Hf;
    const int steps_total = isB ? Hb : Hf;
    const int P_full = steps_total >> 6;
    const int rem    = steps_total & 63;
    const int P      = P_full + (rem ? 1 : 0);
    const float* rowb = y_pred + (size_t)bb * T_ * C_;

    double a0 = 0.0, a1 = 0.0, a2 = 0.0, a3 = 0.0;
    double Lsum = 0.0;
    int E = 0;

    const int fs = (wv - 1) * 8;

    auto fillw = [&](int phf) {
        char* bbw = ldsb + (phf & 1) * BUFSZ;
        const int kb_ = phf * PH + fs;
        float g10,g30,gb0, g11,g31,gb1, g12,g32,gb2, g13,g33,gb3,
              g14,g34,gb4, g15,g35,gb5, g16,g36,gb6, g17,g37,gb7;
        int t0_,t1_,t2_,t3_,t4_,t5_,t6_,t7_;
#define FR(i_) (isB ? (N - (kb_ + i_)) : (1 + kb_ + i_))
        t0_=FR(0); t1_=FR(1); t2_=FR(2); t3_=FR(3);
        t4_=FR(4); t5_=FR(5); t6_=FR(6); t7_=FR(7);
#undef FR
        {
            const float* r_;
            r_ = rowb + (size_t)min(max(t0_,1),N) * C_; g10=r_[e1]; g30=r_[e3]; gb0=r_[BLANK];
            r_ = rowb + (size_t)min(max(t1_,1),N) * C_; g11=r_[e1]; g31=r_[e3]; gb1=r_[BLANK];
            r_ = rowb + (size_t)min(max(t2_,1),N) * C_; g12=r_[e1]; g32=r_[e3]; gb2=r_[BLANK];
            r_ = rowb + (size_t)min(max(t3_,1),N) * C_; g13=r_[e1]; g33=r_[e3]; gb3=r_[BLANK];
            r_ = rowb + (size_t)min(max(t4_,1),N) * C_; g14=r_[e1]; g34=r_[e3]; gb4=r_[BLANK];
            r_ = rowb + (size_t)min(max(t5_,1),N) * C_; g15=r_[e1]; g35=r_[e3]; gb5=r_[BLANK];
            r_ = rowb + (size_t)min(max(t6_,1),N) * C_; g16=r_[e1]; g36=r_[e3]; gb6=r_[BLANK];
            r_ = rowb + (size_t)min(max(t7_,1),N) * C_; g17=r_[e1]; g37=r_[e3]; gb7=r_[BLANK];
        }
        __builtin_amdgcn_sched_barrier(0);
        float lgs_ = 0.f;
#define PWR(i_, T_V, G1, G3, GB) { \
        float rb_ = GB + 1e-7f; \
        float rc_ = frcp(rb_); \
        char* q_ = bbw + (fs + i_) * FSTRIDE; \
        *(double2*)(q_ + 16 * l) = make_double2((double)((G1 + 1e-7f) * rc_), \
                                                 (double)((G3 + 1e-7f) * rc_)); \
        bool ok_ = isB ? (T_V >= Hf + 1 && T_V <= N) : (T_V >= 1 && T_V <= Hf); \
        lgs_ += ok_ ? flog2(rb_) : 0.f; }
        PWR(0, t0_, g10, g30, gb0); PWR(1, t1_, g11, g31, gb1);
        PWR(2, t2_, g12, g32, gb2); PWR(3, t3_, g13, g33, gb3);
        PWR(4, t4_, g14, g34, gb4); PWR(5, t5_, g15, g35, gb5);
        PWR(6, t6_, g16, g36, gb6); PWR(7, t7_, g17, g37, gb7);
#undef PWR
        if (l == 0) lgs[phf & 1][wv - 1] = lgs_;
    };

#define DECLF(Pr) double Pr##q1, Pr##q3
#define DECLB(Pr) double Pr##q1, Pr##q3, Pr##q1n
#define LDF(Pr, fi_) { \
    double2 v_ = *(const double2*)(bbp_ + (fi_) * FSTRIDE + 16 * l); \
    Pr##q1 = v_.x; Pr##q3 = v_.y; }
#define LDFB(Pr, fi_) { \
    double2 v_ = *(const double2*)(bbp_ + (fi_) * FSTRIDE + 16 * l); \
    Pr##q1 = v_.x; Pr##q3 = v_.y; \
    Pr##q1n = *(const double*)(bbp_ + (fi_) * FSTRIDE + 16 * ((l + 1) & 63)); }

#define STEPQ(Pr) { \
    int slo_ = dpp_mov<DPP_WAVE_SHR1>(__double2loint(a3)); \
    int shi_ = dpp_mov<DPP_WAVE_SHR1>(__double2hiint(a3)); \
    double pm1_ = __hiloint2double(shi_, slo_); \
    double n0_ = a0 + pm1_; \
    double n1_ = (a1 + a0 + m1 * pm1_) * Pr##q1; \
    double n2_ = a2 + a1; \
    double n3_ = (a3 + a2 + m3 * a1) * Pr##q3; \
    a0 = n0_; a1 = n1_; a2 = n2_; a3 = n3_; }

#define STEPB(Pr) { \
    int n0lo_ = dpp_mov<DPP_WAVE_SHL1>(__double2loint(a0)); \
    int n0hi_ = dpp_mov<DPP_WAVE_SHL1>(__double2hiint(a0)); \
    int n1lo_ = dpp_mov<DPP_WAVE_SHL1>(__double2loint(a1)); \
    int n1hi_ = dpp_mov<DPP_WAVE_SHL1>(__double2hiint(a1)); \
    double b0n_ = __hiloint2double(n0hi_, n0lo_); \
    double b1n_ = __hiloint2double(n1hi_, n1lo_); \
    double c1_ = a1 * Pr##q1; \
    double c3_ = a3 * Pr##q3; \
    double c1n_ = b1n_ * Pr##q1n; \
    double n0_ = a0 + c1_; \
    double n1_ = c1_ + a2 + m3 * c3_; \
    double n2_ = a2 + c3_; \
    double n3_ = c3_ + b0n_ + m1n * c1n_; \
    a0 = n0_; a1 = n1_; a2 = n2_; a3 = n3_; }

#define DPPMAX(u_, ctrl_) { unsigned t_ = (unsigned)dpp_mov<ctrl_>((int)(u_)); \
    u_ = max(u_, t_); }
#define RESCALE() { \
    unsigned u_ = max(max((unsigned)__double2hiint(a0), (unsigned)__double2hiint(a1)), \
                      max((unsigned)__double2hiint(a2), (unsigned)__double2hiint(a3))); \
    DPPMAX(u_, DPP_ROW_SHR1); \
    DPPMAX(u_, DPP_ROW_SHR2); \
    DPPMAX(u_, DPP_ROW_SHR4); \
    DPPMAX(u_, DPP_ROW_SHR8); \
    unsigned g_ = max(max((unsigned)__builtin_amdgcn_readlane((int)u_, 15), \
                          (unsigned)__builtin_amdgcn_readlane((int)u_, 31)), \
                      max((unsigned)__builtin_amdgcn_readlane((int)u_, 47), \
                          (unsigned)__builtin_amdgcn_readlane((int)u_, 63))); \
    int kk_ = (int)(g_ >> 20); \
    if (kk_ > 0) { \
        double f_ = __hiloint2double((2046 - kk_) << 20, 0); \
        a0 *= f_; a1 *= f_; a2 *= f_; a3 *= f_; \
        E += kk_ - 1023; } }

// validated 32-step forward body (2 RESCALEs, cadence 16)
#define BODY32F(base_) { \
    const char* bbp_ = (base_); \
    DECLF(A0); DECLF(A1); DECLF(A2); DECLF(A3); \
    DECLF(B0); DECLF(B1); DECLF(B2); DECLF(B3); \
    LDF(A0,0); LDF(A1,1); LDF(A2,2); LDF(A3,3); \
    LDF(B0,4); LDF(B1,5); LDF(B2,6); LDF(B3,7); \
    STEPQ(A0); STEPQ(A1); STEPQ(A2); STEPQ(A3); \
    LDF(A0,8); LDF(A1,9); LDF(A2,10); LDF(A3,11); \
    STEPQ(B0); STEPQ(B1); STEPQ(B2); STEPQ(B3); \
    LDF(B0,12); LDF(B1,13); LDF(B2,14); LDF(B3,15); \
    STEPQ(A0); STEPQ(A1); STEPQ(A2); STEPQ(A3); \
    LDF(A0,16); LDF(A1,17); LDF(A2,18); LDF(A3,19); \
    STEPQ(B0); STEPQ(B1); STEPQ(B2); STEPQ(B3); RESCALE(); \
    LDF(B0,20); LDF(B1,21); LDF(B2,22); LDF(B3,23); \
    STEPQ(A0); STEPQ(A1); STEPQ(A2); STEPQ(A3); \
    LDF(A0,24); LDF(A1,25); LDF(A2,26); LDF(A3,27); \
    STEPQ(B0); STEPQ(B1); STEPQ(B2); STEPQ(B3); \
    LDF(B0,28); LDF(B1,29); LDF(B2,30); LDF(B3,31); \
    STEPQ(A0); STEPQ(A1); STEPQ(A2); STEPQ(A3); \
    STEPQ(B0); STEPQ(B1); STEPQ(B2); STEPQ(B3); RESCALE(); }

#define BODY32B(base_) { \
    const char* bbp_ = (base_); \
    DECLB(A0); DECLB(A1); DECLB(A2); DECLB(A3); \
    DECLB(B0); DECLB(B1); DECLB(B2); DECLB(B3); \
    LDFB(A0,0); LDFB(A1,1); LDFB(A2,2); LDFB(A3,3); \
    LDFB(B0,4); LDFB(B1,5); LDFB(B2,6); LDFB(B3,7); \
    STEPB(A0); STEPB(A1); STEPB(A2); STEPB(A3); \
    LDFB(A0,8); LDFB(A1,9); LDFB(A2,10); LDFB(A3,11); \
    STEPB(B0); STEPB(B1); STEPB(B2); STEPB(B3); \
    LDFB(B0,12); LDFB(B1,13); LDFB(B2,14); LDFB(B3,15); \
    STEPB(A0); STEPB(A1); STEPB(A2); STEPB(A3); \
    LDFB(A0,16); LDFB(A1,17); LDFB(A2,18); LDFB(A3,19); \
    STEPB(B0); STEPB(B1); STEPB(B2); STEPB(B3); RESCALE(); \
    LDFB(B0,20); LDFB(B1,21); LDFB(B2,22); LDFB(B3,23); \
    STEPB(A0); STEPB(A1); STEPB(A2); STEPB(A3); \
    LDFB(A0,24); LDFB(A1,25); LDFB(A2,26); LDFB(A3,27); \
    STEPB(B0); STEPB(B1); STEPB(B2); STEPB(B3); \
    LDFB(B0,28); LDFB(B1,29); LDFB(B2,30); LDFB(B3,31); \
    STEPB(A0); STEPB(A1); STEPB(A2); STEPB(A3); \
    STEPB(B0); STEPB(B1); STEPB(B2); STEPB(B3); RESCALE(); }

    if (wv >= 1) {
        fillw(0);
    } else if (!isB) {
        __builtin_amdgcn_s_setprio(1);
        float pb0_ = rowb[BLANK] + 1e-7f;
        float p10_ = rowb[e1]    + 1e-7f;
        a0 = (l == 0) ? 1.0 : 0.0;
        a1 = (l == 0) ? (double)(p10_ / pb0_) : 0.0;
        Lsum = (double)flog2(pb0_);
    } else {
        __builtin_amdgcn_s_setprio(1);
        const int llb = lab_len[bb];
        const int pa = 2 * llb, pq = 2 * llb - 1;
        a0 = (4 * l     == pa) ? 1.0 : 0.0;
        a1 = (4 * l + 1 == pq) ? 1.0 : 0.0;
        a2 = (4 * l + 2 == pa) ? 1.0 : 0.0;
        a3 = (4 * l + 3 == pq) ? 1.0 : 0.0;
    }
    __syncthreads();

    for (int ph = 0; ph < P; ++ph) {
        if (wv >= 1) {
            if (ph + 1 < P) fillw(ph + 1);
        } else {
            const char* base_ = ldsb + (ph & 1) * BUFSZ;
            const int steps = (ph < P_full) ? 64 : rem;
            if (steps == 64) {
                if (!isB) { BODY32F(base_); BODY32F(base_ + 32 * FSTRIDE); }
                else      { BODY32B(base_); BODY32B(base_ + 32 * FSTRIDE); }
            } else {
                const char* bbp_ = base_;
                if (!isB) {
                    for (int k_ = 0; k_ < steps; ++k_) {
                        DECLF(Tq); LDF(Tq, k_); STEPQ(Tq);
                        if ((k_ & 15) == 15) RESCALE();
                    }
                } else {
                    for (int k_ = 0; k_ < steps; ++k_) {
                        DECLB(Tq); LDFB(Tq, k_); STEPB(Tq);
                        if ((k_ & 15) == 15) RESCALE();
                    }
                }
                RESCALE();
            }
            float lg_ = 0.f;
            #pragma unroll
            for (int w_ = 0; w_ < NPROD; ++w_) lg_ += lgs[ph & 1][w_];
            Lsum += (double)lg_;
        }
        __syncthreads();
    }

    if (wv == 0) {
        double* AV = (isB ? AVb : AVf) + bb * 256;
        AV[4 * l + 0] = a0; AV[4 * l + 1] = a1;
        AV[4 * l + 2] = a2; AV[4 * l + 3] = a3;
        if (l == 0) {
            Ls[bb * 2 + (isB ? 1 : 0)] = Lsum;
            Es[bb * 2 + (isB ? 1 : 0)] = E;
        }
    }
}

__global__ __launch_bounds__(64) void ctc_combine_kernel(
    const double* __restrict__ AVf, const double* __restrict__ AVb,
    const double* __restrict__ Ls, const int* __restrict__ Es,
    float* __restrict__ out)
{
    const int b = blockIdx.x;
    const int l = threadIdx.x;
    const double* f = AVf + b * 256;
    const double* g = AVb + b * 256;
    double d = f[4*l+0]*g[4*l+0] + f[4*l+1]*g[4*l+1]
             + f[4*l+2]*g[4*l+2] + f[4*l+3]*g[4*l+3];
    d += __shfl_xor(d, 1);  d += __shfl_xor(d, 2);  d += __shfl_xor(d, 4);
    d += __shfl_xor(d, 8);  d += __shfl_xor(d, 16); d += __shfl_xor(d, 32);
    if (l == 0) {
        double Ltot = Ls[b * 2] + Ls[b * 2 + 1];
        int    Etot = Es[b * 2] + Es[b * 2 + 1];
        int hi = __double2hiint(d), lo = __double2loint(d);
        int ke = (hi >> 20) & 0x7FF;
        double mant = __hiloint2double((hi & 0x000FFFFF) | (1023 << 20), lo);
        float r = flog2((float)mant) + (float)(ke - 1023 + Etot) + (float)Ltot;
        out[b] = -r * LN2F;
    }
}

extern "C" void kernel_launch(void* const* d_in, const int* in_sizes, int n_in,
                              void* d_out, int out_size, void* d_ws, size_t ws_size,
                              hipStream_t stream) {
    const int*   y_true  = (const int*)d_in[0];
    const float* y_pred  = (const float*)d_in[1];
    const int*   in_len  = (const int*)d_in[2];
    const int*   lab_len = (const int*)d_in[3];
    float*       out     = (float*)d_out;

    double* AVf = (double*)d_ws;                 // [64][256]
    double* AVb = AVf + 64 * 256;                // [64][256]
    double* Ls  = AVb + 64 * 256;                // [64][2]
    int*    Es  = (int*)(Ls + 128);              // [64][2]

    ctc_split_kernel<<<128, 576, 0, stream>>>(y_true, y_pred, in_len, lab_len,
                                              AVf, AVb, Ls, Es);
    ctc_combine_kernel<<<64, 64, 0, stream>>>(AVf, AVb, Ls, Es, out);
}